// Round 1
// baseline (461.924 us; speedup 1.0000x reference)
//
#include <hip/hip_runtime.h>

#define DIM 128
#define NA 4096
#define NWORDS 16384
#define MAXNZ 256
#define KW 23
#define PAD 11

// ---------------- gather rows: out[i][:] = tab[idx[i]][:] (float4) ----------------
__global__ void k_gather(float* __restrict__ out, const float* __restrict__ tab,
                         const int* __restrict__ idx) {
  int t = blockIdx.x * blockDim.x + threadIdx.x;   // over n*32 float4s
  int r = t >> 5, c = t & 31;
  ((float4*)out)[t] = ((const float4*)(tab + (size_t)idx[r] * DIM))[c];
}

// ---------------- adjacency scan -> per-row (col,val) lists ----------------
__global__ void k_adj_scan(int* __restrict__ cnt, int* __restrict__ colx,
                           float* __restrict__ valx, const float* __restrict__ adj) {
  int w = threadIdx.x >> 6, lane = threadIdx.x & 63;
  int row = blockIdx.x * 4 + w;
  const float* ar = adj + (size_t)row * NA;
  int count = 0;
  unsigned long long ltm = (1ull << lane) - 1ull;
  for (int c = lane; c < NA; c += 64) {
    float v = ar[c];
    unsigned long long m = __ballot(v != 0.0f);
    if (v != 0.0f) {
      int off = count + (int)__popcll(m & ltm);
      if (off < MAXNZ) { colx[row * MAXNZ + off] = c; valx[row * MAXNZ + off] = v; }
    }
    count += (int)__popcll(m);
  }
  if (lane == 0) cnt[row] = count;
}

// ---------------- C[M,128] = relu(A[M,128] @ W[128,128]^T + b) ----------------
// 64x64 tile per block, 256 threads, 4x4 register tile, no LDS transpose.
__global__ __launch_bounds__(256) void k_linear_relu(
    float* __restrict__ out, const float* __restrict__ A,
    const float* __restrict__ W, const float* __restrict__ bias) {
  __shared__ float As[64 * 132];
  __shared__ float Ws[64 * 132];
  int mt = blockIdx.x >> 1, nt = blockIdx.x & 1;
  int r0 = mt * 64, c0 = nt * 64;
  int tid = threadIdx.x;
  for (int q = tid; q < 64 * 32; q += 256) {
    int row = q >> 5, c4 = q & 31;
    *(float4*)&As[row * 132 + c4 * 4] = *(const float4*)&A[(size_t)(r0 + row) * DIM + c4 * 4];
    *(float4*)&Ws[row * 132 + c4 * 4] = *(const float4*)&W[(size_t)(c0 + row) * DIM + c4 * 4];
  }
  __syncthreads();
  int rgr = tid & 15, cgr = tid >> 4;
  float acc[4][4] = {};
  #pragma unroll 4
  for (int k4 = 0; k4 < 32; ++k4) {
    int kk = ((k4 + rgr) & 31) * 4;     // per-lane k-rotation: spreads LDS banks
    float4 a[4], w[4];
    #pragma unroll
    for (int i = 0; i < 4; ++i) a[i] = *(const float4*)&As[(rgr * 4 + i) * 132 + kk];
    #pragma unroll
    for (int j = 0; j < 4; ++j) w[j] = *(const float4*)&Ws[(cgr * 4 + j) * 132 + kk];
    #pragma unroll
    for (int i = 0; i < 4; ++i)
      #pragma unroll
      for (int j = 0; j < 4; ++j)
        acc[i][j] += a[i].x * w[j].x + a[i].y * w[j].y + a[i].z * w[j].z + a[i].w * w[j].w;
  }
  #pragma unroll
  for (int i = 0; i < 4; ++i) {
    int r = r0 + rgr * 4 + i;
    int c = c0 + cgr * 4;
    float4 bv = *(const float4*)&bias[c];
    float4 o;
    o.x = acc[i][0] + bv.x; o.y = acc[i][1] + bv.y;
    o.z = acc[i][2] + bv.z; o.w = acc[i][3] + bv.w;
    o.x = o.x > 0.f ? o.x : 0.f; o.y = o.y > 0.f ? o.y : 0.f;
    o.z = o.z > 0.f ? o.z : 0.f; o.w = o.w > 0.f ? o.w : 0.f;
    *(float4*)&out[(size_t)r * DIM + c] = o;
  }
}

// ---------------- xs[r][:] += sum_i val_i * hs[col_i][:] ----------------
__global__ void k_spmm(float* __restrict__ xs, const float* __restrict__ hs,
                       const int* __restrict__ cnt, const int* __restrict__ colx,
                       const float* __restrict__ valx, const float* __restrict__ adj) {
  int r = blockIdx.x, d = threadIdx.x;
  int n = cnt[r];
  float acc = xs[(size_t)r * DIM + d];
  if (n <= MAXNZ) {
    for (int i = 0; i < n; ++i)
      acc += valx[r * MAXNZ + i] * hs[(size_t)colx[r * MAXNZ + i] * DIM + d];
  } else {              // safety fallback, statistically never taken
    for (int c = 0; c < NA; ++c) {
      float a = adj[(size_t)r * NA + c];
      if (a != 0.f) acc += a * hs[(size_t)c * DIM + d];
    }
  }
  xs[(size_t)r * DIM + d] = acc;
}

// ---------------- column mean (scaled), atomic partials ----------------
__global__ void k_mean(float* __restrict__ out, const float* __restrict__ in,
                       int rows_per_block, float scale) {
  __shared__ float red[256];
  int d = threadIdx.x & 127, half = threadIdx.x >> 7;
  int r0 = blockIdx.x * rows_per_block;
  float acc = 0.f;
  for (int r = r0 + half; r < r0 + rows_per_block; r += 2)
    acc += in[(size_t)r * DIM + d];
  red[threadIdx.x] = acc;
  __syncthreads();
  if (half == 0) atomicAdd(&out[d], (acc + red[threadIdx.x + 128]) * scale);
}

// ---------------- 23x23 conv (1 channel) + bias + leaky relu ----------------
#define CROWS 32
#define TROWS 54      // CROWS + 22
#define TCOLS 150     // DIM + 22
#define TSTR  156     // padded stride (16B-aligned, spreads banks)
__global__ __launch_bounds__(256) void k_conv(
    float* __restrict__ out, const float* __restrict__ in,
    const float* __restrict__ cw, const float* __restrict__ cb) {
  __shared__ float tile[TROWS * TSTR];
  int r0 = blockIdx.x * CROWS;
  int tid = threadIdx.x;
  for (int p = tid; p < TROWS * TCOLS; p += 256) {
    int rr = p / TCOLS, cc = p - rr * TCOLS;
    int gr = r0 - PAD + rr, gc = cc - PAD;
    float v = 0.f;
    if ((unsigned)gr < NWORDS && (unsigned)gc < DIM) v = in[(size_t)gr * DIM + gc];
    tile[rr * TSTR + cc] = v;
  }
  __syncthreads();
  int rl = tid >> 3, cg = tid & 7;
  int c0 = cg * 16;                    // 16 output columns per thread
  float acc[16] = {};
  float bias = cb[0];
  for (int dy = 0; dy < KW; ++dy) {
    const float* trow = &tile[(rl + dy) * TSTR + c0];
    float v[40];
    #pragma unroll
    for (int q = 0; q < 10; ++q) {
      float4 t4 = *(const float4*)&trow[q * 4];
      v[q * 4 + 0] = t4.x; v[q * 4 + 1] = t4.y;
      v[q * 4 + 2] = t4.z; v[q * 4 + 3] = t4.w;
    }
    const float* wr = cw + dy * KW;    // uniform address -> scalar loads
    #pragma unroll
    for (int dx = 0; dx < KW; ++dx) {
      float wv = wr[dx];
      #pragma unroll
      for (int i = 0; i < 16; ++i) acc[i] += wv * v[i + dx];
    }
  }
  size_t ob = (size_t)(r0 + rl) * DIM + c0;
  #pragma unroll
  for (int q = 0; q < 4; ++q) {
    float4 o;
    float x0 = acc[q*4+0] + bias, x1 = acc[q*4+1] + bias;
    float x2 = acc[q*4+2] + bias, x3 = acc[q*4+3] + bias;
    o.x = x0 > 0.f ? x0 : 0.01f * x0;
    o.y = x1 > 0.f ? x1 : 0.01f * x1;
    o.z = x2 > 0.f ? x2 : 0.01f * x2;
    o.w = x3 > 0.f ? x3 : 0.01f * x3;
    *(float4*)&out[ob + q * 4] = o;
  }
}

// ---------------- h = relu(W_att @ compound + b), 128 threads ----------------
__global__ void k_h(float* __restrict__ h, const float* __restrict__ comp,
                    const float* __restrict__ W, const float* __restrict__ b) {
  __shared__ float c[DIM];
  int j = threadIdx.x;
  c[j] = comp[j];
  __syncthreads();
  float acc = b[j];
  for (int k = 0; k < DIM; ++k) acc += c[k] * W[j * DIM + k];
  h[j] = acc > 0.f ? acc : 0.f;
}

// ---------------- attw[r] = tanh(dot(h, hsA[r])), wave per row ----------------
__global__ void k_attw(float* __restrict__ attw, const float* __restrict__ hsA,
                       const float* __restrict__ h) {
  int w = threadIdx.x >> 6, lane = threadIdx.x & 63;
  int row = blockIdx.x * 4 + w;
  float2 hv = ((const float2*)h)[lane];
  float2 xv = ((const float2*)(hsA + (size_t)row * DIM))[lane];
  float d = hv.x * xv.x + hv.y * xv.y;
  for (int o = 32; o > 0; o >>= 1) d += __shfl_xor(d, o);
  if (lane == 0) attw[row] = tanhf(d);
}

// ---------------- protein[d] = (1/N) sum_r attw[r]*hsA[r][d] ----------------
__global__ void k_protein(float* __restrict__ prot, const float* __restrict__ hsA,
                          const float* __restrict__ attw) {
  __shared__ float red[256];
  int d = threadIdx.x & 127, half = threadIdx.x >> 7;
  int r0 = blockIdx.x * 128;
  float acc = 0.f;
  for (int r = r0 + half; r < r0 + 128; r += 2)
    acc += attw[r] * hsA[(size_t)r * DIM + d];
  red[threadIdx.x] = acc;
  __syncthreads();
  if (half == 0) atomicAdd(&prot[d], (acc + red[threadIdx.x + 128]) * (1.f / NWORDS));
}

// ---------------- output MLP: cat(256) -> 2x relu-linear(256) -> scalar ----------------
__global__ __launch_bounds__(256) void k_final(
    float* __restrict__ out, const float* __restrict__ comp, const float* __restrict__ prot,
    const float* __restrict__ Wo, const float* __restrict__ bo,
    const float* __restrict__ Wi, const float* __restrict__ bi) {
  __shared__ float cat[256];
  __shared__ float red[256];
  int t = threadIdx.x;
  cat[t] = t < 128 ? comp[t] : prot[t - 128];
  __syncthreads();
  for (int l = 0; l < 2; ++l) {
    const float* Wl = Wo + l * 256 * 256;
    float acc = bo[l * 256 + t];
    for (int k = 0; k < 256; ++k) acc += cat[k] * Wl[t * 256 + k];
    __syncthreads();
    cat[t] = acc > 0.f ? acc : 0.f;
    __syncthreads();
  }
  red[t] = cat[t] * Wi[t];
  __syncthreads();
  for (int s = 128; s > 0; s >>= 1) {
    if (t < s) red[t] += red[t + s];
    __syncthreads();
  }
  if (t == 0) out[0] = red[0] + bi[0];
}

extern "C" void kernel_launch(void* const* d_in, const int* in_sizes, int n_in,
                              void* d_out, int out_size, void* d_ws, size_t ws_size,
                              hipStream_t stream) {
  const int*   fingerprints = (const int*)d_in[0];
  const float* adjacency    = (const float*)d_in[1];
  const int*   words        = (const int*)d_in[2];
  const float* emb_fp       = (const float*)d_in[3];
  const float* emb_word     = (const float*)d_in[4];
  const float* W_gnn_w      = (const float*)d_in[5];
  const float* W_gnn_b      = (const float*)d_in[6];
  const float* conv_w       = (const float*)d_in[7];
  const float* conv_b       = (const float*)d_in[8];
  const float* W_att_w      = (const float*)d_in[9];
  const float* W_att_b      = (const float*)d_in[10];
  const float* W_out_w      = (const float*)d_in[11];
  const float* W_out_b      = (const float*)d_in[12];
  const float* W_int_w      = (const float*)d_in[13];
  const float* W_int_b      = (const float*)d_in[14];
  float* out = (float*)d_out;

  float* xs   = (float*)d_ws;               // 524288
  float* hsb  = xs   + 524288;              // 524288
  float* valx = hsb  + 524288;              // 1048576
  float* pa   = valx + 1048576;             // 2097152
  float* pb   = pa   + 2097152;             // 2097152
  float* hsA  = pb   + 2097152;             // 2097152
  float* attw = hsA  + 2097152;             // 16384
  float* small= attw + 16384;               // 512
  int*   colx = (int*)(small + 512);        // 1048576
  int*   cntv = colx + 1048576;             // 4096
  float* comp = small, *prot = small + 128, *hvec = small + 256;

  hipMemsetAsync(small, 0, 512 * sizeof(float), stream);

  // ---- GNN ----
  k_gather<<<512, 256, 0, stream>>>(xs, emb_fp, fingerprints);
  k_adj_scan<<<1024, 256, 0, stream>>>(cntv, colx, valx, adjacency);
  for (int l = 0; l < 3; ++l) {
    k_linear_relu<<<128, 256, 0, stream>>>(hsb, xs, W_gnn_w + l * DIM * DIM, W_gnn_b + l * DIM);
    k_spmm<<<NA, 128, 0, stream>>>(xs, hsb, cntv, colx, valx, adjacency);
  }
  k_mean<<<32, 256, 0, stream>>>(comp, xs, 128, 1.0f / NA);

  // ---- protein CNN ----
  k_gather<<<2048, 256, 0, stream>>>(pa, emb_word, words);
  k_conv<<<512, 256, 0, stream>>>(pb, pa, conv_w + 0 * 529, conv_b + 0);
  k_conv<<<512, 256, 0, stream>>>(pa, pb, conv_w + 1 * 529, conv_b + 1);
  k_conv<<<512, 256, 0, stream>>>(pb, pa, conv_w + 2 * 529, conv_b + 2);

  // ---- attention ----
  k_linear_relu<<<512, 256, 0, stream>>>(hsA, pb, W_att_w, W_att_b);
  k_h<<<1, 128, 0, stream>>>(hvec, comp, W_att_w, W_att_b);
  k_attw<<<4096, 256, 0, stream>>>(attw, hsA, hvec);
  k_protein<<<128, 256, 0, stream>>>(prot, hsA, attw);

  // ---- output MLP ----
  k_final<<<1, 256, 0, stream>>>(out, comp, prot, W_out_w, W_out_b, W_int_w, W_int_b);
}

// Round 3
// 383.973 us; speedup vs baseline: 1.2030x; 1.2030x over previous
//
#include <hip/hip_runtime.h>

#define DIM 128
#define NA 4096
#define NWORDS 16384
#define MAXNZ 256
#define KW 23
#define PAD 11

// ---------------- gather rows: out[i][:] = tab[idx[i]][:] (float4) ----------------
__global__ void k_gather(float* __restrict__ out, const float* __restrict__ tab,
                         const int* __restrict__ idx) {
  int t = blockIdx.x * blockDim.x + threadIdx.x;   // over n*32 float4s
  int r = t >> 5, c = t & 31;
  ((float4*)out)[t] = ((const float4*)(tab + (size_t)idx[r] * DIM))[c];
}

// ---------------- adjacency scan -> per-row (col,val) lists ----------------
__global__ void k_adj_scan(int* __restrict__ cnt, int* __restrict__ colx,
                           float* __restrict__ valx, const float* __restrict__ adj) {
  int w = threadIdx.x >> 6, lane = threadIdx.x & 63;
  int row = blockIdx.x * 4 + w;
  const float4* ar = (const float4*)(adj + (size_t)row * NA);
  int count = 0;
  unsigned long long ltm = (1ull << lane) - 1ull;
  for (int c4 = lane; c4 < NA / 4; c4 += 64) {
    float4 v = ar[c4];
    #pragma unroll
    for (int e = 0; e < 4; ++e) {
      float ve = e == 0 ? v.x : e == 1 ? v.y : e == 2 ? v.z : v.w;
      unsigned long long m = __ballot(ve != 0.0f);
      if (ve != 0.0f) {
        int off = count + (int)__popcll(m & ltm);
        if (off < MAXNZ) { colx[row * MAXNZ + off] = c4 * 4 + e; valx[row * MAXNZ + off] = ve; }
      }
      count += (int)__popcll(m);
    }
  }
  if (lane == 0) cnt[row] = count;
}

// ---------------- C[M,128] = relu(A[M,128] @ W[128,128]^T + b) ----------------
__global__ __launch_bounds__(256) void k_linear_relu(
    float* __restrict__ out, const float* __restrict__ A,
    const float* __restrict__ W, const float* __restrict__ bias) {
  __shared__ float As[64 * 132];
  __shared__ float Ws[64 * 132];
  int mt = blockIdx.x >> 1, nt = blockIdx.x & 1;
  int r0 = mt * 64, c0 = nt * 64;
  int tid = threadIdx.x;
  for (int q = tid; q < 64 * 32; q += 256) {
    int row = q >> 5, c4 = q & 31;
    *(float4*)&As[row * 132 + c4 * 4] = *(const float4*)&A[(size_t)(r0 + row) * DIM + c4 * 4];
    *(float4*)&Ws[row * 132 + c4 * 4] = *(const float4*)&W[(size_t)(c0 + row) * DIM + c4 * 4];
  }
  __syncthreads();
  int rgr = tid & 15, cgr = tid >> 4;
  float acc[4][4] = {};
  #pragma unroll 4
  for (int k4 = 0; k4 < 32; ++k4) {
    int kk = ((k4 + rgr) & 31) * 4;
    float4 a[4], w[4];
    #pragma unroll
    for (int i = 0; i < 4; ++i) a[i] = *(const float4*)&As[(rgr * 4 + i) * 132 + kk];
    #pragma unroll
    for (int j = 0; j < 4; ++j) w[j] = *(const float4*)&Ws[(cgr * 4 + j) * 132 + kk];
    #pragma unroll
    for (int i = 0; i < 4; ++i)
      #pragma unroll
      for (int j = 0; j < 4; ++j)
        acc[i][j] += a[i].x * w[j].x + a[i].y * w[j].y + a[i].z * w[j].z + a[i].w * w[j].w;
  }
  #pragma unroll
  for (int i = 0; i < 4; ++i) {
    int r = r0 + rgr * 4 + i;
    int c = c0 + cgr * 4;
    float4 bv = *(const float4*)&bias[c];
    float4 o;
    o.x = acc[i][0] + bv.x; o.y = acc[i][1] + bv.y;
    o.z = acc[i][2] + bv.z; o.w = acc[i][3] + bv.w;
    o.x = o.x > 0.f ? o.x : 0.f; o.y = o.y > 0.f ? o.y : 0.f;
    o.z = o.z > 0.f ? o.z : 0.f; o.w = o.w > 0.f ? o.w : 0.f;
    *(float4*)&out[(size_t)r * DIM + c] = o;
  }
}

// ---------------- xs[r][:] += sum_i val_i * hs[col_i][:] ----------------
__global__ void k_spmm(float* __restrict__ xs, const float* __restrict__ hs,
                       const int* __restrict__ cnt, const int* __restrict__ colx,
                       const float* __restrict__ valx, const float* __restrict__ adj) {
  __shared__ int scol[MAXNZ];
  __shared__ float sval[MAXNZ];
  int r = blockIdx.x, d = threadIdx.x;
  int n = cnt[r];
  int m = (n <= MAXNZ) ? n : 0;
  for (int i = d; i < m; i += 128) {
    scol[i] = colx[r * MAXNZ + i];
    sval[i] = valx[r * MAXNZ + i];
  }
  __syncthreads();
  float acc = xs[(size_t)r * DIM + d];
  if (n <= MAXNZ) {
    for (int i = 0; i < n; ++i)
      acc += sval[i] * hs[(size_t)scol[i] * DIM + d];
  } else {              // safety fallback, statistically never taken
    for (int c = 0; c < NA; ++c) {
      float a = adj[(size_t)r * NA + c];
      if (a != 0.f) acc += a * hs[(size_t)c * DIM + d];
    }
  }
  xs[(size_t)r * DIM + d] = acc;
}

// ---------------- column mean (scaled), atomic partials ----------------
__global__ void k_mean(float* __restrict__ out, const float* __restrict__ in,
                       int rows_per_block, float scale) {
  __shared__ float red[256];
  int d = threadIdx.x & 127, half = threadIdx.x >> 7;
  int r0 = blockIdx.x * rows_per_block;
  float acc = 0.f;
  for (int r = r0 + half; r < r0 + rows_per_block; r += 2)
    acc += in[(size_t)r * DIM + d];
  red[threadIdx.x] = acc;
  __syncthreads();
  if (half == 0) atomicAdd(&out[d], (acc + red[threadIdx.x + 128]) * scale);
}

// ---------------- 23x23 conv (1 channel) + bias + leaky relu ----------------
// Bank-conflict-free layout: lanes 0..15 of each issue phase are 16 consecutive
// rows at one col-group; TSTR=164 floats (41 16B-groups, 41%8==1 odd) makes the
// 16 rows cover all 8 bank-groups exactly twice -> 2-way (free).
#define CROWS 32
#define TROWS 54      // CROWS + 22
#define TCOLS 150     // DIM + 22
#define TSTR  164
__global__ __launch_bounds__(256) void k_conv(
    float* __restrict__ out, const float* __restrict__ in,
    const float* __restrict__ cw, const float* __restrict__ cb) {
  __shared__ float tile[TROWS * TSTR];
  int r0 = blockIdx.x * CROWS;
  int tid = threadIdx.x;
  for (int p = tid; p < TROWS * TCOLS; p += 256) {
    int rr = p / TCOLS, cc = p - rr * TCOLS;
    int gr = r0 - PAD + rr, gc = cc - PAD;
    float v = 0.f;
    if ((unsigned)gr < NWORDS && (unsigned)gc < DIM) v = in[(size_t)gr * DIM + gc];
    tile[rr * TSTR + cc] = v;
  }
  __syncthreads();
  int rl = tid & 31, cg = tid >> 5;     // wave phase = 16 consecutive rows
  int c0 = cg * 16;
  float acc[16] = {};
  float bias = cb[0];
  for (int dy = 0; dy < KW; ++dy) {
    const float* trow = &tile[(rl + dy) * TSTR + c0];
    float v[40];
    #pragma unroll
    for (int q = 0; q < 10; ++q) {
      float4 t4 = *(const float4*)&trow[q * 4];
      v[q * 4 + 0] = t4.x; v[q * 4 + 1] = t4.y;
      v[q * 4 + 2] = t4.z; v[q * 4 + 3] = t4.w;
    }
    const float* wr = cw + dy * KW;
    #pragma unroll
    for (int dx = 0; dx < KW; ++dx) {
      float wv = wr[dx];
      #pragma unroll
      for (int i = 0; i < 16; ++i) acc[i] += wv * v[i + dx];
    }
  }
  size_t ob = (size_t)(r0 + rl) * DIM + c0;
  #pragma unroll
  for (int q = 0; q < 4; ++q) {
    float4 o;
    float x0 = acc[q*4+0] + bias, x1 = acc[q*4+1] + bias;
    float x2 = acc[q*4+2] + bias, x3 = acc[q*4+3] + bias;
    o.x = x0 > 0.f ? x0 : 0.01f * x0;
    o.y = x1 > 0.f ? x1 : 0.01f * x1;
    o.z = x2 > 0.f ? x2 : 0.01f * x2;
    o.w = x3 > 0.f ? x3 : 0.01f * x3;
    *(float4*)&out[ob + q * 4] = o;
  }
}

// ---------------- h = relu(W_att @ compound + b), 128 threads ----------------
__global__ void k_h(float* __restrict__ h, const float* __restrict__ comp,
                    const float* __restrict__ W, const float* __restrict__ b) {
  __shared__ float c[DIM];
  int j = threadIdx.x;
  c[j] = comp[j];
  __syncthreads();
  float acc = b[j];
  #pragma unroll
  for (int k4 = 0; k4 < 32; ++k4) {
    float4 w4 = *(const float4*)&W[j * DIM + k4 * 4];
    acc += c[k4*4+0] * w4.x + c[k4*4+1] * w4.y + c[k4*4+2] * w4.z + c[k4*4+3] * w4.w;
  }
  h[j] = acc > 0.f ? acc : 0.f;
}

// ---------------- fused: attw = tanh(h . hsA[r]); prot += attw*hsA/N ----------------
__global__ __launch_bounds__(256) void k_attprot(
    float* __restrict__ prot, const float* __restrict__ hsA, const float* __restrict__ h) {
  __shared__ float lw[128];
  __shared__ float red[256];
  int tid = threadIdx.x;
  int w = tid >> 6, lane = tid & 63;
  int r0 = blockIdx.x * 128;
  float2 hv = ((const float2*)h)[lane];
  for (int rr = w; rr < 128; rr += 4) {
    float2 xv = ((const float2*)(hsA + (size_t)(r0 + rr) * DIM))[lane];
    float dt = hv.x * xv.x + hv.y * xv.y;
    for (int o = 32; o > 0; o >>= 1) dt += __shfl_xor(dt, o);
    if (lane == 0) lw[rr] = tanhf(dt);
  }
  __syncthreads();
  int d = tid & 127, half = tid >> 7;
  float acc = 0.f;
  for (int rr = half; rr < 128; rr += 2)
    acc += lw[rr] * hsA[(size_t)(r0 + rr) * DIM + d];
  red[tid] = acc;
  __syncthreads();
  if (half == 0) atomicAdd(&prot[d], (acc + red[tid + 128]) * (1.f / NWORDS));
}

// ---------------- output MLP: cat(256) -> 2x relu-linear(256) -> scalar ----------------
__global__ __launch_bounds__(256) void k_final(
    float* __restrict__ out, const float* __restrict__ comp, const float* __restrict__ prot,
    const float* __restrict__ Wo, const float* __restrict__ bo,
    const float* __restrict__ Wi, const float* __restrict__ bi) {
  __shared__ float cat[256];
  __shared__ float wred[4];
  int t = threadIdx.x;
  int w = t >> 6, lane = t & 63;
  cat[t] = t < 128 ? comp[t] : prot[t - 128];
  __syncthreads();
  for (int l = 0; l < 2; ++l) {
    const float* Wl = Wo + l * 256 * 256;
    float acc = bo[l * 256 + t];
    #pragma unroll 8
    for (int k4 = 0; k4 < 64; ++k4) {
      float4 w4 = *(const float4*)&Wl[t * 256 + k4 * 4];
      acc += cat[k4*4+0] * w4.x + cat[k4*4+1] * w4.y + cat[k4*4+2] * w4.z + cat[k4*4+3] * w4.w;
    }
    __syncthreads();
    cat[t] = acc > 0.f ? acc : 0.f;
    __syncthreads();
  }
  float r = cat[t] * Wi[t];
  for (int o = 32; o > 0; o >>= 1) r += __shfl_xor(r, o);
  if (lane == 0) wred[w] = r;
  __syncthreads();
  if (t == 0) out[0] = wred[0] + wred[1] + wred[2] + wred[3] + bi[0];
}

extern "C" void kernel_launch(void* const* d_in, const int* in_sizes, int n_in,
                              void* d_out, int out_size, void* d_ws, size_t ws_size,
                              hipStream_t stream) {
  const int*   fingerprints = (const int*)d_in[0];
  const float* adjacency    = (const float*)d_in[1];
  const int*   words        = (const int*)d_in[2];
  const float* emb_fp       = (const float*)d_in[3];
  const float* emb_word     = (const float*)d_in[4];
  const float* W_gnn_w      = (const float*)d_in[5];
  const float* W_gnn_b      = (const float*)d_in[6];
  const float* conv_w       = (const float*)d_in[7];
  const float* conv_b       = (const float*)d_in[8];
  const float* W_att_w      = (const float*)d_in[9];
  const float* W_att_b      = (const float*)d_in[10];
  const float* W_out_w      = (const float*)d_in[11];
  const float* W_out_b      = (const float*)d_in[12];
  const float* W_int_w      = (const float*)d_in[13];
  const float* W_int_b      = (const float*)d_in[14];
  float* out = (float*)d_out;

  float* xs   = (float*)d_ws;               // 524288
  float* hsb  = xs   + 524288;              // 524288
  float* valx = hsb  + 524288;              // 1048576
  float* pa   = valx + 1048576;             // 2097152
  float* pb   = pa   + 2097152;             // 2097152
  float* hsA  = pb   + 2097152;             // 2097152
  float* attw = hsA  + 2097152;             // 16384
  float* small= attw + 16384;               // 512
  int*   colx = (int*)(small + 512);        // 1048576
  int*   cntv = colx + 1048576;             // 4096
  float* comp = small, *prot = small + 128, *hvec = small + 256;
  (void)attw;

  hipMemsetAsync(small, 0, 512 * sizeof(float), stream);

  // ---- GNN ----
  k_gather<<<512, 256, 0, stream>>>(xs, emb_fp, fingerprints);
  k_adj_scan<<<1024, 256, 0, stream>>>(cntv, colx, valx, adjacency);
  for (int l = 0; l < 3; ++l) {
    k_linear_relu<<<128, 256, 0, stream>>>(hsb, xs, W_gnn_w + l * DIM * DIM, W_gnn_b + l * DIM);
    k_spmm<<<NA, 128, 0, stream>>>(xs, hsb, cntv, colx, valx, adjacency);
  }
  k_mean<<<32, 256, 0, stream>>>(comp, xs, 128, 1.0f / NA);

  // ---- protein CNN ----
  k_gather<<<2048, 256, 0, stream>>>(pa, emb_word, words);
  k_conv<<<512, 256, 0, stream>>>(pb, pa, conv_w + 0 * 529, conv_b + 0);
  k_conv<<<512, 256, 0, stream>>>(pa, pb, conv_w + 1 * 529, conv_b + 1);
  k_conv<<<512, 256, 0, stream>>>(pb, pa, conv_w + 2 * 529, conv_b + 2);

  // ---- attention ----
  k_linear_relu<<<512, 256, 0, stream>>>(hsA, pb, W_att_w, W_att_b);
  k_h<<<1, 128, 0, stream>>>(hvec, comp, W_att_w, W_att_b);
  k_attprot<<<128, 256, 0, stream>>>(prot, hsA, hvec);

  // ---- output MLP ----
  k_final<<<1, 256, 0, stream>>>(out, comp, prot, W_out_w, W_out_b, W_int_w, W_int_b);
}